// Round 9
// baseline (295.474 us; speedup 1.0000x reference)
//
#include <hip/hip_runtime.h>
#include <math.h>

#define BB 8192
#define KK 32
#define DD 129      // hyperboloid dim = D + 1
#define VV 2048
#define NN 33       // K + 1
#define TOPK 10
#define WPB 4       // waves (= batches) per block; fully autonomous, no barriers

__device__ __forceinline__ float fast_rcp(float x) { return __builtin_amdgcn_rcpf(x); }
__device__ __forceinline__ float dot4(float4 a, float4 b) {
    return fmaf(a.x, b.x, fmaf(a.y, b.y, fmaf(a.z, b.z, a.w * b.w)));
}

__global__ __launch_bounds__(256) void lr_fused(
    const float* __restrict__ anchor,
    const float* __restrict__ positive,
    const float* __restrict__ neg,
    const float* __restrict__ tree,
    const int* __restrict__ a_idx,
    const int* __restrict__ p_idx,
    const int* __restrict__ n_idx,
    float* __restrict__ out)
{
    // per-wave private LDS slices: no __syncthreads anywhere
    __shared__ float  st_[WPB][NN];     // tree distances
    __shared__ float  sx_[WPB][NN];     // raw -inner (pre-acosh)
    __shared__ float  sd_[WPB][NN];     // d
    __shared__ float4 sitem[WPB][NN];   // {d, rel, disc, 0}

    const int t    = threadIdx.x;
    const int wave = t >> 6;
    const int lane = t & 63;
    const int g    = lane >> 4;        // 4 row-groups per wave
    const int subl = lane & 15;        // 16 lanes per row
    const int b    = blockIdx.x * WPB + wave;

    // ---- tree gather (lanes >=33 clamped dup, discarded) ----
    const int ai  = a_idx[b];
    const int col = (lane == 0) ? p_idx[b]
                                : n_idx[(size_t)b * KK + ((lane < NN ? lane : KK) - 1)];
    const float tg = tree[(size_t)ai * VV + col];
    if (lane < NN) st_[wave][lane] = tg;

    const float* ab = anchor   + (size_t)b * DD;
    const float* pb = positive + (size_t)b * DD;
    const float* nb = neg      + (size_t)b * (KK * DD);

    // anchor: 2 float4 per lane + element 128
    float4 aq0 = *(const float4*)(ab + 4 * subl);
    float4 aq1 = *(const float4*)(ab + 64 + 4 * subl);
    const float a128 = ab[128];

    // ---- 33 rows in 3 chunks of 3 rounds (lower VGPR -> higher occupancy) ----
    #pragma unroll
    for (int c = 0; c < 3; ++c) {
        const float* rp[3];
        float4 v0[3], v1[3];
        float  t128[3];
        #pragma unroll
        for (int k = 0; k < 3; ++k) {
            int row = 4 * (3 * c + k) + g;     // rows 0..35
            if (row > KK) row = KK;            // clamp (dup, discarded)
            rp[k]   = (row == 0) ? pb : (nb + (size_t)(row - 1) * DD);
            v0[k]   = *(const float4*)(rp[k] + 4 * subl);
            v1[k]   = *(const float4*)(rp[k] + 64 + 4 * subl);
            t128[k] = rp[k][128];
        }
        #pragma unroll
        for (int k = 0; k < 3; ++k) {
            float s = dot4(aq0, v0[k]) + dot4(aq1, v1[k]);
            s += __shfl_xor(s, 8, 64);
            s += __shfl_xor(s, 4, 64);
            s += __shfl_xor(s, 2, 64);
            s += __shfl_xor(s, 1, 64);
            int row = 4 * (3 * c + k) + g;
            if (subl == 0 && row < NN) {
                float full = s + a128 * t128[k];          // sum_{0..128} a*v
                // -inner = 2*u0*v0 - full
                sx_[wave][row] = fmaxf(fmaf(2.0f * aq0.x, v0[k].x, -full), 1.0f + 1e-07f);
            }
        }
    }

    // ---- dense acosh pass ----
    float dlane = 0.0f;
    if (lane < NN) {
        float x = sx_[wave][lane];
        dlane = __logf(x + sqrtf(x * x - 1.0f));      // acosh(x)
        sd_[wave][lane] = dlane;
    }

    // ---- maxt via butterfly (lanes >= NN contribute -inf) ----
    float tgm = (lane < NN) ? tg : -3.4e38f;
    #pragma unroll
    for (int off = 32; off > 0; off >>= 1)
        tgm = fmaxf(tgm, __shfl_xor(tgm, off, 64));
    const float maxt = tgm;

    // ---- merged loop: rank from d, ideal-position from t ----
    // descending-rel order == ascending-t order (rel strictly decreasing in t);
    // tie groups share equal rel so the IDCG sum is invariant to intra-tie order.
    float relv = 0.0f, c0 = 0.0f;
    if (lane < NN) {
        relv = (maxt - tg + 1e-06f) * fast_rcp(maxt + 1e-06f);
        int cnt = 0, pos = 0;
        #pragma unroll
        for (int j = 0; j < NN; ++j) {
            float dj = sd_[wave][j];
            float tj = st_[wave][j];
            cnt += (int)((dj < dlane) | ((dj == dlane) & (j < lane)));
            pos += (int)((tj < tg)    | ((tj == tg)    & (j < lane)));
        }
        float disc = (cnt + 1 <= TOPK) ? fast_rcp(log2f((float)(cnt + 2))) : 0.0f;
        if (pos < TOPK) c0 = relv * fast_rcp(log2f((float)(pos + 2)));
        sitem[wave][lane] = make_float4(dlane, relv, disc, 0.0f);
    }

    // ---- IDCG butterfly -> inv broadcast in regs ----
    #pragma unroll
    for (int off = 32; off > 0; off >>= 1) c0 += __shfl_xor(c0, off, 64);
    const float inv = (c0 > 0.0f) ? fast_rcp(c0) : 0.0f;

    // ---- pair sum over i<j (symmetric term: full sum = 2 * this) ----
    float acc = 0.0f;
    #pragma unroll
    for (int it = 0; it < 9; ++it) {
        int p = it * 64 + lane;                  // 0..575
        float vmask = (p < 528) ? 1.0f : 0.0f;
        int pc = (p < 528) ? p : 527;
        int j = (int)((1.0f + sqrtf((float)(8 * pc + 1))) * 0.5f);
        int tj = (j * (j - 1)) >> 1;
        if (tj > pc) { --j; tj = (j * (j - 1)) >> 1; }
        int i = pc - tj;
        float4 Ii = sitem[wave][i];
        float4 Ij = sitem[wave][j];
        float dd    = Ij.x - Ii.x;               // d[j] - d[i]
        float drel  = Ii.y - Ij.y;
        float ddisc = Ii.z - Ij.z;
        float t1  = drel * fabsf(ddisc) * (inv * vmask);   // S * delta (masked)
        float e   = __expf(-dd);
        float num = (drel >= 0.0f) ? 1.0f : e;
        acc = fmaf(t1 * num * fast_rcp(1.0f + e), -dd, acc);
    }
    #pragma unroll
    for (int off = 32; off > 0; off >>= 1) acc += __shfl_xor(acc, off, 64);
    // acc == 0.5 * full pair sum == loss_b ; fold WEIGHT/mean here
    if (lane == 0) atomicAdd(out, acc * (0.15f / (float)BB));
}

extern "C" void kernel_launch(void* const* d_in, const int* in_sizes, int n_in,
                              void* d_out, int out_size, void* d_ws, size_t ws_size,
                              hipStream_t stream)
{
    const float* anchor   = (const float*)d_in[0];
    const float* positive = (const float*)d_in[1];
    const float* neg      = (const float*)d_in[2];
    const float* tree     = (const float*)d_in[3];
    const int*   a_idx    = (const int*)d_in[4];
    const int*   p_idx    = (const int*)d_in[5];
    const int*   n_idx    = (const int*)d_in[6];

    hipMemsetAsync(d_out, 0, (size_t)out_size * sizeof(float), stream);
    lr_fused<<<BB / WPB, 256, 0, stream>>>(anchor, positive, neg, tree,
                                           a_idx, p_idx, n_idx, (float*)d_out);
}